// Round 12
// baseline (301.538 us; speedup 1.0000x reference)
//
#include <hip/hip_runtime.h>
#include <hip/hip_bf16.h>

// GraphConv: out = relu( scatter_add_{edges}( edge_val * (feat @ W)[edge_col] -> edge_row ) )
// Dtypes: feat/W/edge_val = float32, edge_row/col = int32, OUTPUT = float32.
//
// R11 post-mortem: fused gemm_hist still shows ~49MB counts churn -> the interleaved mapping
// (copy = hist_id&7) broke R9's copy==XCD affinity (dispatch presumed round-robin b%8).
// R12: copy = blockIdx&7 (physical index) inside the fused kernel; copy packed into rank's
// high 3 bits (rank = copy<<13 | p, degree < 8192) so scatter just unpacks it.

#define N_NODES 100000
#define N_EDGES 1600000
#define D 128
#define NCOPY 8
#define SCAN_B 1024
#define SCAN_NB ((N_NODES + SCAN_B - 1) / SCAN_B)   // 98
#define GEMM_BLOCKS ((N_NODES + 63) / 64)           // 1563
#define EDGE_BLOCKS ((N_EDGES + 255) / 256)         // 6250

typedef __attribute__((ext_vector_type(8))) short short8;
typedef __attribute__((ext_vector_type(4))) float floatx4;
typedef int  iv2 __attribute__((ext_vector_type(2)));   // nt-store-compatible int2
typedef int  iv4 __attribute__((ext_vector_type(4)));
typedef float fv4 __attribute__((ext_vector_type(4)));  // nt-store-compatible float4

union U16B { uint4 u4; short8 s8; uint u[4]; ushort us[8]; };

__device__ __forceinline__ ushort f32_to_bf16(float f) {
    uint b = __float_as_uint(f);
    return (ushort)((b + 0x7FFFu + ((b >> 16) & 1u)) >> 16);   // RNE; inputs finite
}
__device__ __forceinline__ float bf16_to_f32(ushort u) {
    return __uint_as_float((uint)u << 16);
}

// ---------------- zero counts (8 copies) + lookback state -----------------------------------
__global__ __launch_bounds__(256) void zero_int_kernel(int* __restrict__ p, int n) {
    int i = blockIdx.x * 256 + threadIdx.x;
    if (i < n) p[i] = 0;
}

// ---------------- GEMM body: support = bf16( fp32 feat @ fp32 W ), 16KB LDS ----------------
__device__ __forceinline__ void gemm_body(const float* __restrict__ feat,
                                          const float* __restrict__ W,
                                          ushort* __restrict__ support,
                                          ushort* __restrict__ Bp /*64*D*/, int bid) {
    const int tid = threadIdx.x;
    const int wave = tid >> 6, lane = tid & 63;
    const int row0 = bid * 64 + wave * 16;
    const bool active = (row0 < N_NODES);     // wave-uniform
    const int m = lane & 15, g = lane >> 4;

    floatx4 acc[8];
    const floatx4 z = {0.f, 0.f, 0.f, 0.f};
    #pragma unroll
    for (int t = 0; t < 8; t++) acc[t] = z;

    const float* arow = feat + (size_t)(row0 + m) * D;
    #pragma unroll
    for (int h = 0; h < 2; h++) {             // two k-halves of 64
        if (h) __syncthreads();               // prev readers done before overwrite
        for (int e = tid; e < 64 * D; e += 256) {
            int kk = e >> 7, n = e & 127;
            Bp[(((kk >> 3) * D + n) << 3) | (kk & 7)] = f32_to_bf16(W[(h * 64 + kk) * D + n]);
        }
        __syncthreads();
        if (active) {
            #pragma unroll
            for (int ss = 0; ss < 2; ss++) {  // k-steps of 32 within half
                const int s = h * 2 + ss;
                float4 a0 = *(const float4*)(arow + s * 32 + g * 8);
                float4 a1 = *(const float4*)(arow + s * 32 + g * 8 + 4);
                U16B a;
                a.us[0] = f32_to_bf16(a0.x); a.us[1] = f32_to_bf16(a0.y);
                a.us[2] = f32_to_bf16(a0.z); a.us[3] = f32_to_bf16(a0.w);
                a.us[4] = f32_to_bf16(a1.x); a.us[5] = f32_to_bf16(a1.y);
                a.us[6] = f32_to_bf16(a1.z); a.us[7] = f32_to_bf16(a1.w);
                #pragma unroll
                for (int t = 0; t < 8; t++) { // 8 col-tiles of 16
                    const int chunk = (ss * 4 + g) * D + t * 16 + m;
                    U16B b; b.u4 = *(const uint4*)(Bp + chunk * 8);
                    acc[t] = __builtin_amdgcn_mfma_f32_16x16x32_bf16(a.s8, b.s8, acc[t], 0, 0, 0);
                }
            }
        }
    }
    if (active) {
        // C/D: col = lane&15, row = (lane>>4)*4 + reg  (m89-verified)
        #pragma unroll
        for (int t = 0; t < 8; t++) {
            #pragma unroll
            for (int r = 0; r < 4; r++) {
                const int row = row0 + g * 4 + r;
                const int col = t * 16 + m;
                support[(size_t)row * D + col] = f32_to_bf16(acc[t][r]);
            }
        }
    }
}

// ---------------- hist body: XCD-affine copy (physical blockIdx&7), copy packed in rank -----
__device__ __forceinline__ void hist_body(const int* __restrict__ edge_row,
                                          int* __restrict__ counts,   // [NCOPY][N]
                                          ushort* __restrict__ rank, int hb, int copy) {
    int e = hb * 256 + threadIdx.x;
    if (e >= N_EDGES) return;
    const int p = atomicAdd(&counts[copy * N_NODES + edge_row[e]], 1);
    rank[e] = (ushort)((copy << 13) | p);     // degree < 8192, NCOPY=8 -> fits 16 bits
}

// ---------------- fused gemm || hist, interleaved (every 5th block is gemm) -----------------
__global__ __launch_bounds__(256) void gemm_hist_kernel(const float* __restrict__ feat,
                                                        const float* __restrict__ W,
                                                        ushort* __restrict__ support,
                                                        const int* __restrict__ edge_row,
                                                        int* __restrict__ counts,
                                                        ushort* __restrict__ rank) {
    __shared__ ushort Bp[64 * D];   // 16 KB
    const int b = blockIdx.x;
    const int q = b / 5, r = b - q * 5;       // 7813 blocks: b%5==0 -> gemm (1563), else hist
    if (r == 0)
        gemm_body(feat, W, support, Bp, q);
    else
        hist_body(edge_row, counts, rank, b - q - 1, b & (NCOPY - 1));  // copy = physical idx
}

// ---------------- single-pass scan: fold 8 copies + PARALLEL decoupled lookback -------------
__global__ __launch_bounds__(SCAN_B) void scan_kernel(int* __restrict__ counts,  // -> bases
                                                      int* __restrict__ offsets,
                                                      uint* __restrict__ st) {
    __shared__ int wsum[SCAN_B / 64];
    __shared__ int s_run, s_base;
    const int tid = threadIdx.x, b = blockIdx.x;
    const int gid = b * SCAN_B + tid;
    const int lane = tid & 63, wave = tid >> 6;

    int tot = 0;
    if (gid < N_NODES) {
        int pre[NCOPY];
        #pragma unroll
        for (int k = 0; k < NCOPY; k++) {
            int v = counts[k * N_NODES + gid];
            pre[k] = tot; tot += v;
        }
        #pragma unroll
        for (int k = 0; k < NCOPY; k++) counts[k * N_NODES + gid] = pre[k];  // per-copy bases
    }

    int x = tot;                               // inclusive wave scan of row totals
    #pragma unroll
    for (int d = 1; d < 64; d <<= 1) {
        int y = __shfl_up(x, d, 64);
        if (lane >= d) x += y;
    }
    if (lane == 63) wsum[wave] = x;
    __syncthreads();
    if (tid == 0) {
        int run = 0;
        #pragma unroll
        for (int w = 0; w < SCAN_B / 64; w++) { int t = wsum[w]; wsum[w] = run; run += t; }
        s_run = run;
        __hip_atomic_store(&st[b], (1u << 30) | (uint)run,
                           __ATOMIC_RELEASE, __HIP_MEMORY_SCOPE_AGENT);
    }
    __syncthreads();
    if (wave == 0) {
        int P = 0;
        int base = b;
        bool done = (b == 0);
        while (!done) {
            const int j = base - 1 - lane;     // lane l inspects predecessor b-1-l
            uint w;
            if (j >= 0) {
                do {
                    w = __hip_atomic_load(&st[j], __ATOMIC_ACQUIRE, __HIP_MEMORY_SCOPE_AGENT);
                } while ((w >> 30) == 0u);
            } else w = 2u << 30;               // virtual prefix 0 before block 0
            const unsigned long long m2 = __ballot((w >> 30) == 2u);
            int contrib;
            if (m2) {
                const int fl = (int)__ffsll(m2) - 1;   // nearest published prefix
                contrib = (lane <= fl) ? (int)(w & 0x3FFFFFFFu) : 0;
                done = true;
            } else {
                contrib = (int)(w & 0x3FFFFFFFu);      // 64 aggregates, keep walking
                base -= 64;
            }
            #pragma unroll
            for (int mm = 1; mm < 64; mm <<= 1) contrib += __shfl_xor(contrib, mm, 64);
            P += contrib;
        }
        if (lane == 0) {
            __hip_atomic_store(&st[b], (2u << 30) | (uint)(P + s_run),
                               __ATOMIC_RELEASE, __HIP_MEMORY_SCOPE_AGENT);
            s_base = P;
        }
    }
    __syncthreads();
    if (gid < N_NODES) offsets[gid] = s_base + wsum[wave] + (x - tot);
    if (gid == 0) offsets[N_NODES] = N_EDGES;
}

// ---------------- scatter (no atomics; copy unpacked from rank; one nt 8B store/edge) -------
__global__ __launch_bounds__(256) void scatter_kernel(const int* __restrict__ edge_row,
                                                      const int* __restrict__ edge_col,
                                                      const float* __restrict__ edge_val,
                                                      const int* __restrict__ offsets,
                                                      const int* __restrict__ counts,  // bases
                                                      const ushort* __restrict__ rank,
                                                      iv2* __restrict__ epack) {
    int e = blockIdx.x * 256 + threadIdx.x;
    if (e >= N_EDGES) return;
    const uint rr = rank[e];
    const int copy = (int)(rr >> 13);
    const int r = edge_row[e];
    const int p = offsets[r] + counts[copy * N_NODES + r] + (int)(rr & 0x1FFFu);
    iv2 pk;
    pk.x = edge_col[e];
    pk.y = __float_as_int(edge_val[e]);
    __builtin_nontemporal_store(pk, epack + p);
}

// ---------------- Accumulate: 16 lanes/row, 4-wide unroll, fused ReLU -----------------------
__global__ __launch_bounds__(256) void accum_kernel(const ushort* __restrict__ support,
                                                    const int* __restrict__ offsets,
                                                    const iv2* __restrict__ epack,
                                                    float* __restrict__ out) {
    const int tid = threadIdx.x;
    const int row  = (blockIdx.x * 256 + tid) >> 4;       // one 16-lane group per row
    const int part = tid & 15;
    if (row >= N_NODES) return;

    const int start = offsets[row], end = offsets[row + 1];
    float acc0[8], acc1[8];
    #pragma unroll
    for (int i = 0; i < 8; i++) { acc0[i] = 0.f; acc1[i] = 0.f; }

    int e = start;
    if ((e & 1) && e < end) {                 // align to 16B for iv4 loads
        const iv2 pa = epack[e];
        U16B sa; sa.u4 = *(const uint4*)(support + (size_t)pa.x * D + part * 8);
        const float va = __int_as_float(pa.y);
        #pragma unroll
        for (int i = 0; i < 8; i++) acc0[i] += bf16_to_f32(sa.us[i]) * va;
        ++e;
    }
    for (; e + 3 < end; e += 4) {             // 4 gathers in flight
        const iv4 qa = ((const iv4*)(epack + e))[0];      // edges e, e+1
        const iv4 qb = ((const iv4*)(epack + e))[1];      // edges e+2, e+3
        U16B s0; s0.u4 = *(const uint4*)(support + (size_t)qa.x * D + part * 8);
        U16B s1; s1.u4 = *(const uint4*)(support + (size_t)qa.z * D + part * 8);
        U16B s2; s2.u4 = *(const uint4*)(support + (size_t)qb.x * D + part * 8);
        U16B s3; s3.u4 = *(const uint4*)(support + (size_t)qb.z * D + part * 8);
        const float v0 = __int_as_float(qa.y);
        const float v1 = __int_as_float(qa.w);
        const float v2 = __int_as_float(qb.y);
        const float v3 = __int_as_float(qb.w);
        #pragma unroll
        for (int i = 0; i < 8; i++) {
            acc0[i] += bf16_to_f32(s0.us[i]) * v0;
            acc1[i] += bf16_to_f32(s1.us[i]) * v1;
            acc0[i] += bf16_to_f32(s2.us[i]) * v2;
            acc1[i] += bf16_to_f32(s3.us[i]) * v3;
        }
    }
    for (; e < end; ++e) {
        const iv2 pa = epack[e];
        U16B sa; sa.u4 = *(const uint4*)(support + (size_t)pa.x * D + part * 8);
        const float va = __int_as_float(pa.y);
        #pragma unroll
        for (int i = 0; i < 8; i++) acc0[i] += bf16_to_f32(sa.us[i]) * va;
    }

    fv4 lo, hi;
    lo.x = fmaxf(acc0[0] + acc1[0], 0.f); lo.y = fmaxf(acc0[1] + acc1[1], 0.f);
    lo.z = fmaxf(acc0[2] + acc1[2], 0.f); lo.w = fmaxf(acc0[3] + acc1[3], 0.f);
    hi.x = fmaxf(acc0[4] + acc1[4], 0.f); hi.y = fmaxf(acc0[5] + acc1[5], 0.f);
    hi.z = fmaxf(acc0[6] + acc1[6], 0.f); hi.w = fmaxf(acc0[7] + acc1[7], 0.f);
    float* dst = out + (size_t)row * D + part * 8;
    __builtin_nontemporal_store(lo, (fv4*)dst);        // out has zero reuse: don't pollute
    __builtin_nontemporal_store(hi, (fv4*)(dst + 4));  // L2/L3 (support gather lives there)
}

// ================= Fallback path (R3 atomic spmm) if ws too small ===========================
__global__ __launch_bounds__(256) void gemm_kernel(const float* __restrict__ feat,
                                                   const float* __restrict__ W,
                                                   ushort* __restrict__ support) {
    __shared__ ushort Bp[64 * D];
    gemm_body(feat, W, support, Bp, blockIdx.x);
}
__global__ __launch_bounds__(256) void zero_f4_kernel(float4* __restrict__ acc, int n4) {
    int i = blockIdx.x * 256 + threadIdx.x;
    if (i < n4) acc[i] = make_float4(0.f, 0.f, 0.f, 0.f);
}
__global__ __launch_bounds__(256) void spmm_kernel(const ushort* __restrict__ support,
                                                   const float* __restrict__ edge_val,
                                                   const int* __restrict__ edge_row,
                                                   const int* __restrict__ edge_col,
                                                   float* __restrict__ out) {
    const long gtid = (long)blockIdx.x * 256 + threadIdx.x;
    const int edge = (int)(gtid >> 4);
    const int part = (int)(gtid & 15);
    if (edge >= N_EDGES) return;
    const int col = edge_col[edge];
    const int row = edge_row[edge];
    const float v = edge_val[edge];
    U16B s; s.u4 = *(const uint4*)(support + (size_t)col * D + part * 8);
    float* dst = out + (size_t)row * D + part * 8;
    #pragma unroll
    for (int i = 0; i < 8; i++) unsafeAtomicAdd(dst + i, bf16_to_f32(s.us[i]) * v);
}
__global__ __launch_bounds__(256) void relu_kernel(float4* __restrict__ out, int n4) {
    int i = blockIdx.x * 256 + threadIdx.x;
    if (i >= n4) return;
    float4 a = out[i];
    a.x = fmaxf(a.x, 0.f); a.y = fmaxf(a.y, 0.f);
    a.z = fmaxf(a.z, 0.f); a.w = fmaxf(a.w, 0.f);
    out[i] = a;
}

extern "C" void kernel_launch(void* const* d_in, const int* in_sizes, int n_in,
                              void* d_out, int out_size, void* d_ws, size_t ws_size,
                              hipStream_t stream) {
    (void)in_sizes; (void)n_in; (void)out_size;
    const float* feat     = (const float*)d_in[0];
    const float* W        = (const float*)d_in[1];
    const float* edge_val = (const float*)d_in[2];
    const int*   edge_row = (const int*)d_in[3];
    const int*   edge_col = (const int*)d_in[4];
    float* out = (float*)d_out;

    // ws layout (~45.2 MB; counts and st contiguous so one zero pass covers both)
    char* ws = (char*)d_ws;
    size_t o = 0;
    ushort* support = (ushort*)(ws + o); o += (size_t)N_NODES * D * sizeof(ushort);  // 25.6 MB
    int*    offsets = (int*)(ws + o);    o += ((size_t)(N_NODES + 1) * 4 + 15) & ~15ull;
    int*    counts  = (int*)(ws + o);    o += (size_t)NCOPY * N_NODES * 4;           // 3.2 MB
    uint*   st      = (uint*)(ws + o);   o += 128 * 4;                               // lookback
    ushort* rank    = (ushort*)(ws + o); o += (size_t)N_EDGES * 2;                   // 3.2 MB
    iv2*    epack   = (iv2*)(ws + o);    o += (size_t)N_EDGES * 8;                   // 12.8 MB
    const size_t needed = o;

    if (ws_size >= needed) {
        const int nz = NCOPY * N_NODES + 128;   // counts + st in one pass
        zero_int_kernel<<<(nz + 255) / 256, 256, 0, stream>>>(counts, nz);
        gemm_hist_kernel<<<GEMM_BLOCKS + EDGE_BLOCKS, 256, 0, stream>>>(
            feat, W, support, edge_row, counts, rank);
        scan_kernel<<<SCAN_NB, SCAN_B, 0, stream>>>(counts, offsets, st);
        scatter_kernel<<<EDGE_BLOCKS, 256, 0, stream>>>(edge_row, edge_col, edge_val,
                                                        offsets, counts, rank, epack);
        accum_kernel<<<(N_NODES * 16 + 255) / 256, 256, 0, stream>>>(support, offsets,
                                                                     epack, out);
    } else {
        // R3 fallback: atomic spmm into d_out
        const int n4 = N_NODES * D / 4;
        zero_f4_kernel<<<(n4 + 255) / 256, 256, 0, stream>>>((float4*)out, n4);
        gemm_kernel<<<GEMM_BLOCKS, 256, 0, stream>>>(feat, W, support);
        spmm_kernel<<<(int)(((long)N_EDGES * 16 + 255) / 256), 256, 0, stream>>>(
            support, edge_val, edge_row, edge_col, out);
        relu_kernel<<<(n4 + 255) / 256, 256, 0, stream>>>((float4*)out, n4);
    }
}